// Round 8
// baseline (135.318 us; speedup 1.0000x reference)
//
#include <hip/hip_runtime.h>

#define D 256
#define S 2048
#define B 8
#define DSQ (D * D)   // 65536
#define INV3 (1.0f / 2043.0f)   // 1/(S-5)

typedef __bf16 bf16x8 __attribute__((ext_vector_type(8)));
typedef float f32x4 __attribute__((ext_vector_type(4)));

__device__ __forceinline__ unsigned short f2bf(float f) {
    union { float f; unsigned int u; } v; v.f = f;
    unsigned int u = v.u;
    u += 0x7fffu + ((u >> 16) & 1u);   // RTNE
    return (unsigned short)(u >> 16);
}

__device__ __forceinline__ void gl2lds16(const void* g, void* l) {
    __builtin_amdgcn_global_load_lds(
        (const __attribute__((address_space(1))) void*)g,
        (__attribute__((address_space(3))) void*)l, 16, 0, 0);
}

// ---------------- K1: bf16 cast + partial sums + Cbs build -----------------
// 512 blocks x 256 thr; block = 32 rows of one b. x is HBM-cold here (L3
// flushed by the harness ws-poison) — the one full-BW pass over x.
__global__ __launch_bounds__(256) void k_prep(const float* __restrict__ x,
                                              const float* __restrict__ comp,
                                              const float* __restrict__ basis,
                                              const float* __restrict__ root,
                                              unsigned short* __restrict__ xh,
                                              float* __restrict__ part,
                                              unsigned short* __restrict__ Cbs) {
    int blk = blockIdx.x;            // b*64 + chunk
    int tid = threadIdx.x;
    int b = blk >> 6, chunk = blk & 63;
    __shared__ float ps[4][D];
    int rg = tid >> 6;               // 0..3 row-group (8 rows each)
    int c4 = (tid & 63) << 2;
    int row0 = chunk * 32 + rg * 8;
    const float4* xb = (const float4*)(x + ((size_t)b * S + row0) * D + c4);
    ushort4* dst = (ushort4*)(xh + ((size_t)(1 + b * S + row0)) * D + c4);
    float4 s = {0.f, 0.f, 0.f, 0.f};
    #pragma unroll
    for (int i = 0; i < 8; ++i) {
        float4 v = xb[(size_t)i * 64];
        ushort4 o;
        o.x = f2bf(v.x); o.y = f2bf(v.y); o.z = f2bf(v.z); o.w = f2bf(v.w);
        dst[(size_t)i * 64] = o;
        s.x += v.x; s.y += v.y; s.z += v.z; s.w += v.w;
    }
    *(float4*)&ps[rg][c4] = s;

    if (blk < 160) {                 // Cbs[step][n][32] bf16 (independent of x)
        int step = blk >> 2, q = blk & 3;
        int ji = step >> 3, kc = step & 7;
        int n = tid;
        float a0 = (ji == 2) ? 1.f : 0.f;
        float a1 = (ji == 1 || ji == 3) ? 0.5f : 0.f;
        float a2 = (ji == 0 || ji == 4) ? 0.5f : 0.f;
        float ar = (ji == 1) ? 1.f : 0.f;
        float cb0 = a0 * comp[0] + a1 * comp[2] + a2 * comp[4] - INV3 * comp[6];
        float cb1 = a0 * comp[1] + a1 * comp[3] + a2 * comp[5] - INV3 * comp[7];
        unsigned short buf[8];
        #pragma unroll
        for (int kk = 0; kk < 8; ++kk) {
            int i = kc * 32 + q * 8 + kk;
            buf[kk] = f2bf(cb0 * basis[i * D + n] + cb1 * basis[DSQ + i * D + n]
                           + ar * root[i * D + n]);
        }
        *(uint4*)(Cbs + ((size_t)step * 256 + n) * 32 + q * 8) = *(uint4*)buf;
    }
    __syncthreads();
    if (tid < 64)
        *(float4*)&part[(size_t)blk * D + tid * 4] =
            *(float4*)&ps[0][tid * 4] + *(float4*)&ps[1][tid * 4] +
            *(float4*)&ps[2][tid * 4] + *(float4*)&ps[3][tid * 4];
}

// ---------------- K2: bulk MFMA + in-block Tb + boundary -------------------
// 256 blocks x 256 thr (1/CU). blk -> nblk=blk&1, mblk=(blk>>1)&15, b=blk>>5.
// Tile 128m x 128n, 4 waves. After the K-loop each block reduces part->tot,
// GEMVs its 128-col Tb slice, writes epilogue; mblk 0/15 blocks also do the
// boundary rows for their n-half.
__global__ __launch_bounds__(256) void k_main(
        const unsigned short* __restrict__ xh,   // padded rows: [1 + B*S + 3]
        const unsigned short* __restrict__ Cbs,  // [40][256][32]
        const float* __restrict__ part,          // [512][256]
        const float* __restrict__ x,
        const float* __restrict__ comp, const float* __restrict__ basis,
        const float* __restrict__ root, const float* __restrict__ bias,
        float* __restrict__ out) {
    __shared__ __align__(16) unsigned short xs[132 * 256];    // 67584 B
    __shared__ float tot[D];
    __shared__ float tbp[2][128];
    __shared__ float z0[D], z1[D], xr[D], bp[128];
    const int tid  = threadIdx.x;
    const int lane = tid & 63;
    const int w    = tid >> 6;
    const int wm   = w & 1;             // m-half
    const int wn   = w >> 1;            // n-quarter within the block's n-half
    const int blk  = blockIdx.x;        // 0..255
    const int nblk = blk & 1;
    const int mblk = (blk >> 1) & 15;
    const int b    = blk >> 5;
    const int t0   = mblk << 7;
    const size_t rowbase = (size_t)b * S + t0;   // padded row of x[b][t0-1]

    // stage x tile: 132 rows x 512B = 4224 16B-chunks, swizzled
    #pragma unroll
    for (int q = 0; q < 16; ++q) {
        int F = (q * 256 + tid) * 16;
        int r = F >> 9;
        int c16 = (F >> 4) & 31;
        int gc = (c16 & 24) | ((c16 ^ r) & 7);
        gl2lds16((const char*)xh + ((rowbase + r) << 9) + (gc << 4), (char*)xs + F);
    }
    if (tid < 128) {
        int F = (4096 + tid) * 16;
        int r = F >> 9;
        int c16 = (F >> 4) & 31;
        int gc = (c16 & 24) | ((c16 ^ r) & 7);
        gl2lds16((const char*)xh + ((rowbase + r) << 9) + (gc << 4), (char*)xs + F);
    }
    __syncthreads();

    const int rlo = lane & 15, q4 = lane >> 4;
    const int nstrip = nblk * 128 + wn * 64;
    const int mbase  = wm * 64;

    #define BFRAG(st, nt) (*(const bf16x8*)(Cbs + \
        (((size_t)(st) * 256 + nstrip + (nt) * 16 + rlo) << 5) + (q4 << 3)))
    #define AFRAG(st, mt) (*(const bf16x8*)((const char*)xs + \
        (((mbase + (mt) * 16 + rlo + ((st) >> 3))) << 9) + \
        (((((st) & 7) * 4 + q4) & 24 | ((((st) & 7) * 4 + q4) ^ \
          (mbase + (mt) * 16 + rlo + ((st) >> 3))) & 7) << 4)))

    f32x4 acc[4][4] = {};
    bf16x8 bb[4][4];
    bf16x8 aa[2][4];
    #pragma unroll
    for (int nt = 0; nt < 4; ++nt) {
        bb[0][nt] = BFRAG(0, nt); bb[1][nt] = BFRAG(1, nt); bb[2][nt] = BFRAG(2, nt);
    }
    #pragma unroll
    for (int mt = 0; mt < 4; ++mt) aa[0][mt] = AFRAG(0, mt);

    #pragma unroll
    for (int step = 0; step < 40; ++step) {
        const int pfB = (step + 3 < 40) ? step + 3 : 39;
        #pragma unroll
        for (int nt = 0; nt < 4; ++nt) bb[(step + 3) & 3][nt] = BFRAG(pfB, nt);
        const int pfA = (step + 1 < 40) ? step + 1 : 39;
        #pragma unroll
        for (int mt = 0; mt < 4; ++mt) aa[(step + 1) & 1][mt] = AFRAG(pfA, mt);

        #pragma unroll
        for (int mt = 0; mt < 4; ++mt)
            #pragma unroll
            for (int nt = 0; nt < 4; ++nt)
                acc[mt][nt] = __builtin_amdgcn_mfma_f32_16x16x32_bf16(
                    aa[step & 1][mt], bb[step & 3][nt], acc[mt][nt], 0, 0, 0);
    }
    #undef BFRAG
    #undef AFRAG

    // ---- tot[k] = sum over 64 chunks of part (L2/L3-warm, coalesced) ----
    {
        float s = 0.f;
        const float* pp = part + (size_t)b * 64 * D + tid;
        #pragma unroll 8
        for (int c = 0; c < 64; ++c) s += pp[(size_t)c * D];
        tot[tid] = s;
    }
    __syncthreads();

    // ---- Tb slice GEMV: this block's 128 n-cols ----
    {
        int o = nblk * 128 + (tid & 127);
        int kh = tid >> 7;
        float c6 = comp[6], c7 = comp[7];
        float a = 0.f;
        #pragma unroll 4
        for (int kk = 0; kk < 128; ++kk) {
            int k = kh * 128 + kk;
            a += tot[k] * (c6 * basis[k * D + o] + c7 * basis[DSQ + k * D + o]);
        }
        tbp[kh][tid & 127] = a;
    }
    __syncthreads();

    // ---- epilogue: C/D layout col=lane&15, row=(lane>>4)*4+i ----
    const int col = lane & 15, rq = (lane >> 4) << 2;
    #pragma unroll
    for (int nt = 0; nt < 4; ++nt) {
        int nloc = wn * 64 + nt * 16 + col;
        int n = nblk * 128 + nloc;
        float tb = bias[n] + INV3 * (tbp[0][nloc] + tbp[1][nloc]);
        #pragma unroll
        for (int mt = 0; mt < 4; ++mt) {
            #pragma unroll
            for (int i = 0; i < 4; ++i) {
                int t = t0 + mbase + mt * 16 + rq + i;
                if (t >= 1 && t <= S - 4)
                    out[(((size_t)b * S + t) << 8) + n] = acc[mt][nt][i] + tb;
            }
        }
    }

    // ---- boundary rows on the owning tiles ----
    if (mblk != 0 && mblk != 15) return;
    const int ntb = (mblk == 0) ? 1 : 3;
    const float* xb = x + (size_t)b * S * D;
    for (int bi = 0; bi < ntb; ++bi) {
        int t = (mblk == 0) ? 0 : (S - 3 + bi);
        {   // gather phase: thread = channel i
            int i = tid;
            float x_t = xb[(size_t)t * D + i];
            float v0 = (t + 1 < S) ? xb[(size_t)(t + 1) * D + i] : 0.f;
            float d1 = 1.f + ((t + 2 < S) ? 1.f : 0.f);
            float v1 = (x_t + ((t + 2 < S) ? xb[(size_t)(t + 2) * D + i] : 0.f)) / d1;
            float s2 = ((t - 1 >= 0) ? xb[(size_t)(t - 1) * D + i] : 0.f)
                     + ((t + 3 < S) ? xb[(size_t)(t + 3) * D + i] : 0.f);
            int d2i = ((t - 1 >= 0) ? 1 : 0) + ((t + 3 < S) ? 1 : 0);
            float v2 = d2i ? s2 / (float)d2i : 0.f;
            float wsum = 0.f;
            for (int s = t - 1; s <= t + 3; ++s)
                if (s >= 0 && s < S) wsum += xb[(size_t)s * D + i];
            int d3i = ((t - 1 > 0) ? (t - 1) : 0) + ((S - 4 - t > 0) ? (S - 4 - t) : 0);
            float v3 = d3i ? (tot[i] - wsum) / (float)d3i : 0.f;
            __syncthreads();   // reuse guard across bi iterations
            z0[i] = comp[0] * v0 + comp[2] * v1 + comp[4] * v2 + comp[6] * v3;
            z1[i] = comp[1] * v0 + comp[3] * v1 + comp[5] * v2 + comp[7] * v3;
            xr[i] = x_t;
        }
        __syncthreads();
        {   // GEMV: 2 threads per output col (k split), this block's n-half
            int o = nblk * 128 + (tid & 127);
            int kh = tid >> 7;
            float a = 0.f;
            #pragma unroll 4
            for (int kk = 0; kk < 128; ++kk) {
                int k = kh * 128 + kk;
                a += z0[k] * basis[k * D + o] + z1[k] * basis[DSQ + k * D + o]
                   + xr[k] * root[k * D + o];
            }
            if (kh) bp[tid & 127] = a;
            __syncthreads();
            if (!kh)
                out[(((size_t)b * S + t) << 8) + o] = a + bp[tid & 127] + bias[o];
        }
    }
}

// ---------------- launch ----------------

extern "C" void kernel_launch(void* const* d_in, const int* in_sizes, int n_in,
                              void* d_out, int out_size, void* d_ws, size_t ws_size,
                              hipStream_t stream) {
    const float* x     = (const float*)d_in[0];
    const float* comp  = (const float*)d_in[1];
    const float* basis = (const float*)d_in[2];
    const float* root  = (const float*)d_in[3];
    const float* bias  = (const float*)d_in[4];
    float* out = (float*)d_out;

    char* ws = (char*)d_ws;
    float* part         = (float*)(ws);                     // 512 KB
    unsigned short* Cbs = (unsigned short*)(ws + 524288);   // 640 KB
    unsigned short* xh  = (unsigned short*)(ws + 1179648);  // 16392 rows * 512 B

    k_prep<<<512, 256, 0, stream>>>(x, comp, basis, root, xh, part, Cbs);
    k_main<<<256, 256, 0, stream>>>(xh, Cbs, part, x, comp, basis, root, bias, out);
}